// Round 11
// baseline (89.873 us; speedup 1.0000x reference)
//
#include <hip/hip_runtime.h>

// Problem constants (from reference): B=32, N=2048, S=64, D=1024, fp32.
constexpr int B = 32;
constexpr int N = 2048;
constexpr int S = 64;
constexpr int D = 1024;
constexpr int ROW4 = D / 4;                 // 256 float4 per row
constexpr int BLOCK = 256;                  // one row per block-wide op
constexpr int CHUNKS_PER_BATCH = 64;
constexpr int ROWS_PER_CHUNK = N / CHUNKS_PER_BATCH;   // 32 rows = 128 KB
constexpr int GRID = B * CHUNKS_PER_BATCH;  // 2048 blocks = 8/CU
constexpr int DEPTH = 8;                    // rows per register bank
constexpr int MACROS = ROWS_PER_CHUNK / DEPTH;  // 4 macro-iters

typedef float f4 __attribute__((ext_vector_type(4)));

// R10 + software-pipelined double-banked register staging.
// R10 drained all loads at each store burst (load8 -> store8 sawtooth);
// here the NEXT 8 loads are issued BEFORE the current 8 stores, keeping
// >=8 loads in flight continuously. Two statically-named banks (rule #20:
// no runtime bank index -> stays in registers). Everything else = R10.
__global__ __launch_bounds__(BLOCK) void copy_fix(
    const f4* __restrict__ state, const f4* __restrict__ substate,
    const float* __restrict__ probs, const int* __restrict__ idx,
    f4* __restrict__ out) {
    __shared__ int win[ROWS_PER_CHUNK];
    const int b = blockIdx.x >> 6;
    const int chunk = blockIdx.x & 63;
    const int rowStart = chunk * ROWS_PER_CHUNK;

    if (threadIdx.x < ROWS_PER_CHUNK) win[threadIdx.x] = 0;
    __syncthreads();
    if (threadIdx.x < S) {
        int r = idx[b * S + threadIdx.x] - rowStart;
        if ((unsigned)r < (unsigned)ROWS_PER_CHUNK)
            atomicMax(&win[r], (int)threadIdx.x + 1);
    }

    const long base = (long)blockIdx.x * (ROWS_PER_CHUNK * ROW4) + threadIdx.x;
    f4 rA[DEPTH], rB[DEPTH];

    // prologue: fill bank A
#pragma unroll
    for (int j = 0; j < DEPTH; ++j) rA[j] = state[base + (long)j * BLOCK];

    // steady state: issue next bank's loads, then store current bank
#pragma unroll
    for (int mi = 0; mi < MACROS - 1; ++mi) {
        const long cur = base + (long)mi * (DEPTH * BLOCK);
        const long nxt = cur + DEPTH * BLOCK;
        if (mi & 1) {       // static parity -> banks fully register-resident
#pragma unroll
            for (int j = 0; j < DEPTH; ++j) rA[j] = state[nxt + (long)j * BLOCK];
#pragma unroll
            for (int j = 0; j < DEPTH; ++j)
                __builtin_nontemporal_store(rB[j], &out[cur + (long)j * BLOCK]);
        } else {
#pragma unroll
            for (int j = 0; j < DEPTH; ++j) rB[j] = state[nxt + (long)j * BLOCK];
#pragma unroll
            for (int j = 0; j < DEPTH; ++j)
                __builtin_nontemporal_store(rA[j], &out[cur + (long)j * BLOCK]);
        }
    }
    // epilogue: store last bank (MACROS-1 = 3, odd -> last loads went to rB)
    {
        const long cur = base + (long)(MACROS - 1) * (DEPTH * BLOCK);
#pragma unroll
        for (int j = 0; j < DEPTH; ++j)
            __builtin_nontemporal_store(((MACROS - 1) & 1) ? rB[j] : rA[j],
                                        &out[cur + (long)j * BLOCK]);
    }

    __syncthreads();  // win[] visible; copy stores drained (vmcnt(0) at barrier)

    // fixup: rewrite selected rows of my chunk (block-uniform branches)
    const long chunkBase = (long)blockIdx.x * (ROWS_PER_CHUNK * ROW4);
    for (int r = 0; r < ROWS_PER_CHUNK; ++r) {
        int w = win[r];
        if (w > 0) {
            int s = w - 1;
            float p = probs[(b << 6) + s];
            long rowBase = chunkBase + (long)r * ROW4;
            f4 g = state[rowBase + threadIdx.x];
            f4 v = substate[((long)(b << 6) + s) * ROW4 + threadIdx.x];
            __builtin_nontemporal_store((1.0f - p) * g + p * v,
                                        &out[rowBase + threadIdx.x]);
        }
    }
}

extern "C" void kernel_launch(void* const* d_in, const int* in_sizes, int n_in,
                              void* d_out, int out_size, void* d_ws, size_t ws_size,
                              hipStream_t stream) {
    const f4*    state    = (const f4*)d_in[0];
    const f4*    substate = (const f4*)d_in[1];
    const int*   idx      = (const int*)d_in[2];
    const float* probs    = (const float*)d_in[3];
    f4*          out      = (f4*)d_out;

    copy_fix<<<GRID, BLOCK, 0, stream>>>(state, substate, probs, idx, out);
}

// Round 12
// 88.195 us; speedup vs baseline: 1.0190x; 1.0190x over previous
//
#include <hip/hip_runtime.h>

// Problem constants (from reference): B=32, N=2048, S=64, D=1024, fp32.
constexpr int B = 32;
constexpr int N = 2048;
constexpr int S = 64;
constexpr int D = 1024;
constexpr int ROW4 = D / 4;                 // 256 float4 per row
constexpr int BLOCK = 256;                  // one row per block-wide op
constexpr int CHUNKS_PER_BATCH = 64;
constexpr int ROWS_PER_CHUNK = N / CHUNKS_PER_BATCH;   // 32 rows = 128 KB
constexpr int GRID = B * CHUNKS_PER_BATCH;  // 2048 blocks = 8/CU

typedef float f4 __attribute__((ext_vector_type(4)));

// FINAL (revert to R10, the measured optimum: 87.75 us = 94% of the 6.29 TB/s
// copy ceiling). Structure: single dispatch; per-block 32-row winner map in
// LDS (last-duplicate-wins via atomicMax over s+1); pure streaming copy with
// 8-deep register batches (load8 -> NT-store8); post-barrier in-block fixup
// rewrites the ~1 selected row per block.
// Levers that mattered (A/B'd): NT stores (2x, R4), plain cached loads so L3
// serves ~50% of state (R6), split copy/fixup logic out of the stream loop
// (+6%, R8), 8-deep register staging (+3.5%, R10). Null/negative: NT load
// hints (R5/R7), branchless select (R5), SW-pipelined double banks (R11).
__global__ __launch_bounds__(BLOCK) void copy_fix(
    const f4* __restrict__ state, const f4* __restrict__ substate,
    const float* __restrict__ probs, const int* __restrict__ idx,
    f4* __restrict__ out) {
    __shared__ int win[ROWS_PER_CHUNK];
    const int b = blockIdx.x >> 6;
    const int chunk = blockIdx.x & 63;
    const int rowStart = chunk * ROWS_PER_CHUNK;

    if (threadIdx.x < ROWS_PER_CHUNK) win[threadIdx.x] = 0;
    __syncthreads();
    if (threadIdx.x < S) {
        int r = idx[b * S + threadIdx.x] - rowStart;
        if ((unsigned)r < (unsigned)ROWS_PER_CHUNK)
            atomicMax(&win[r], (int)threadIdx.x + 1);
    }

    // streaming copy: 4 macro-iters x (load 8 rows -> NT-store 8 rows)
    long gid = (long)blockIdx.x * (ROWS_PER_CHUNK * ROW4) + threadIdx.x;
#pragma unroll
    for (int mi = 0; mi < ROWS_PER_CHUNK / 8; ++mi) {
        f4 r[8];                            // fully static indexing
#pragma unroll
        for (int j = 0; j < 8; ++j) r[j] = state[gid + (long)j * BLOCK];
#pragma unroll
        for (int j = 0; j < 8; ++j)
            __builtin_nontemporal_store(r[j], &out[gid + (long)j * BLOCK]);
        gid += 8L * BLOCK;
    }

    __syncthreads();  // win[] visible; copy stores drained (vmcnt(0) at barrier)

    // fixup: rewrite selected rows of my chunk (block-uniform branches)
    const long chunkBase = (long)blockIdx.x * (ROWS_PER_CHUNK * ROW4);
    for (int r = 0; r < ROWS_PER_CHUNK; ++r) {
        int w = win[r];
        if (w > 0) {
            int s = w - 1;
            float p = probs[(b << 6) + s];
            long rowBase = chunkBase + (long)r * ROW4;
            f4 g = state[rowBase + threadIdx.x];
            f4 v = substate[((long)(b << 6) + s) * ROW4 + threadIdx.x];
            __builtin_nontemporal_store((1.0f - p) * g + p * v,
                                        &out[rowBase + threadIdx.x]);
        }
    }
}

extern "C" void kernel_launch(void* const* d_in, const int* in_sizes, int n_in,
                              void* d_out, int out_size, void* d_ws, size_t ws_size,
                              hipStream_t stream) {
    const f4*    state    = (const f4*)d_in[0];
    const f4*    substate = (const f4*)d_in[1];
    const int*   idx      = (const int*)d_in[2];
    const float* probs    = (const float*)d_in[3];
    f4*          out      = (f4*)d_out;

    copy_fix<<<GRID, BLOCK, 0, stream>>>(state, substate, probs, idx, out);
}